// Round 7
// baseline (72.007 us; speedup 1.0000x reference)
//
#include <hip/hip_runtime.h>

#define NSIDE 256
#define HW    65536   // 256*256
#define NB    4       // batch
#define NMAP  8       // 4 pred + 4 gt
#define NBLK2 128     // pass-2 blocks: 4 images x 32 column-chunks (8 cols each)

typedef unsigned long long u64;

// ws layout
// zzw: u64 [NMAP][4(word)][NSIDE(row)] — per-row fg bitsets, word-major so pass-2
//      loads are lane-coalesced (consecutive rows -> consecutive addresses).
static const size_t ZZ_OFF   = 0;
static const size_t CNT_OFF  = (size_t)NMAP * 4 * NSIDE * 8;   // int counter (64B pad)
static const size_t SLOT_OFF = CNT_OFF + 64;                   // f32 [NBLK2]

// K1: mask bits + per-row fg bitsets. grid NMAP*256 blocks (one per (map,row)).
// Barrier-free, atomic-free; also zeroes the pass-2 completion counter.
__global__ void k_bits(const float* __restrict__ mo, const float* __restrict__ gt,
                       u64* __restrict__ zzw, int* __restrict__ cnt) {
    int m = blockIdx.x >> 8;
    int y = blockIdx.x & 255;
    int x = threadIdx.x;
    int bit;
    if (m < NB) {   // pred: argmax over 2 channels, first-max tie -> 0
        float c0 = mo[(size_t)(m * 2 + 0) * HW + y * NSIDE + x];
        float c1 = mo[(size_t)(m * 2 + 1) * HW + y * NSIDE + x];
        bit = (c1 > c0) ? 1 : 0;
    } else {
        bit = (gt[(size_t)(m - NB) * HW + y * NSIDE + x] > 0.5f) ? 1 : 0;
    }
    u64 fg = __ballot(bit);
    if ((x & 63) == 0)
        zzw[((size_t)m * 4 + (x >> 6)) * NSIDE + y] = fg;   // word (x>>6), row y
    if (blockIdx.x == 0 && x == 0) *cnt = 0;
}

// distance from (uniform) position x to nearest SET bit of {z3:z2:z1:z0}; big if none.
// Branchless ternary chains — no runtime-indexed arrays (no scratch).
__device__ __forceinline__ int nbit(u64 z0, u64 z1, u64 z2, u64 z3,
                                    int xw, u64 loM, u64 hiM, int x) {
    // left: highest set bit at pos <= x
    u64 a0 = (xw == 0) ? (z0 & loM) : z0;
    u64 a1 = (xw < 1) ? 0ull : ((xw == 1) ? (z1 & loM) : z1);
    u64 a2 = (xw < 2) ? 0ull : ((xw == 2) ? (z2 & loM) : z2);
    u64 a3 = (xw < 3) ? 0ull : ((xw == 3) ? (z3 & loM) : z3);
    int msb = -(1 << 20);
    msb = a0 ? (63  - __builtin_clzll(a0)) : msb;
    msb = a1 ? (127 - __builtin_clzll(a1)) : msb;
    msb = a2 ? (191 - __builtin_clzll(a2)) : msb;
    msb = a3 ? (255 - __builtin_clzll(a3)) : msb;
    int dl = x - msb;
    // right: lowest set bit at pos >= x
    u64 b0 = (xw > 0) ? 0ull : (z0 & hiM);
    u64 b1 = (xw > 1) ? 0ull : ((xw == 1) ? (z1 & hiM) : z1);
    u64 b2 = (xw > 2) ? 0ull : ((xw == 2) ? (z2 & hiM) : z2);
    u64 b3 = (xw == 3) ? (z3 & hiM) : z3;
    int lsb = 1 << 20;
    lsb = b3 ? (192 + __builtin_ctzll(b3)) : lsb;
    lsb = b2 ? (128 + __builtin_ctzll(b2)) : lsb;
    lsb = b1 ? (64  + __builtin_ctzll(b1)) : lsb;
    lsb = b0 ? (      __builtin_ctzll(b0)) : lsb;
    int dr = lsb - x;
    return dl < dr ? dl : dr;
}

// K2: row-DT from bitsets + early-exit column DT + err-weighted sum + guard +
// last-block final reduce. grid NBLK2=128 blocks x 1024 threads.
// Block = (image b, 8-column chunk); 2 rounds x 4 column-groups of 256 threads.
__global__ __launch_bounds__(1024) void k_colfinal(const u64* __restrict__ zzw,
                                                   float* __restrict__ slot,
                                                   int* __restrict__ cnt,
                                                   float* __restrict__ out) {
    int b    = blockIdx.x >> 5;
    int xch  = blockIdx.x & 31;
    int g    = threadIdx.x >> 8;   // column group 0..3
    int y    = threadIdx.x & 255;  // row within column
    int wv   = threadIdx.x >> 6;   // wave 0..15 (g = wv>>2)
    int lane = threadIdx.x & 63;

    // row-y bitsets for pred and gt of image b (coalesced: lane-consecutive y)
    u64 p0 = zzw[((size_t)(b * 4) + 0) * NSIDE + y];
    u64 p1 = zzw[((size_t)(b * 4) + 1) * NSIDE + y];
    u64 p2 = zzw[((size_t)(b * 4) + 2) * NSIDE + y];
    u64 p3 = zzw[((size_t)(b * 4) + 3) * NSIDE + y];
    u64 q0 = zzw[((size_t)((NB + b) * 4) + 0) * NSIDE + y];
    u64 q1 = zzw[((size_t)((NB + b) * 4) + 1) * NSIDE + y];
    u64 q2 = zzw[((size_t)((NB + b) * 4) + 2) * NSIDE + y];
    u64 q3 = zzw[((size_t)((NB + b) * 4) + 3) * NSIDE + y];

    __shared__ float cPf[4][NSIDE], cPb[4][NSIDE], cGf[4][NSIDE], cGb[4][NSIDE];
    __shared__ float rP[16], rG[16];
    __shared__ unsigned char oP[16], oG[16];
    __shared__ int lastFlag;
    __shared__ float fin[2];

    // has-fg guard inputs: block covers all 256 rows in each group -> image-wide OR
    int aP = __any(((p0 | p1 | p2 | p3) != 0ull) ? 1 : 0);
    int aG = __any(((q0 | q1 | q2 | q3) != 0ull) ? 1 : 0);
    if (lane == 0) { oP[wv] = aP ? 1 : 0; oG[wv] = aG ? 1 : 0; }

    float accP = 0.0f, accG = 0.0f;   // consumed by thread 0 only
    for (int round = 0; round < 2; ++round) {
        int x  = xch * 8 + round * 4 + g;
        int xw = x >> 6, xb = x & 63;
        u64 loM = (2ull << xb) - 1ull;   // bits 0..xb (xb=63 -> all ones)
        u64 hiM = ~0ull << xb;           // bits xb..63
        // fg-sense targets = zeros of fg = complement; bg-sense targets = fg bits
        int dPf = nbit(~p0, ~p1, ~p2, ~p3, xw, loM, hiM, x);
        int dPb = nbit( p0,  p1,  p2,  p3, xw, loM, hiM, x);
        int dGf = nbit(~q0, ~q1, ~q2, ~q3, xw, loM, hiM, x);
        int dGb = nbit( q0,  q1,  q2,  q3, xw, loM, hiM, x);
        cPf[g][y] = (dPf > 255) ? 1e9f : (float)(dPf * dPf);
        cPb[g][y] = (dPb > 255) ? 1e9f : (float)(dPb * dPb);
        cGf[g][y] = (dGf > 255) ? 1e9f : (float)(dGf * dGf);
        cGb[g][y] = (dGb > 255) ? 1e9f : (float)(dGb * dGb);
        __syncthreads();
        // err = pred bit != gt bit at (y,x); xw uniform -> scalar word select
        u64 pw = (xw == 0) ? p0 : (xw == 1) ? p1 : (xw == 2) ? p2 : p3;
        u64 qw = (xw == 0) ? q0 : (xw == 1) ? q1 : (xw == 2) ? q2 : q3;
        float e = (((pw >> xb) & 1ull) != ((qw >> xb) & 1ull)) ? 1.0f : 0.0f;
        float bPf = cPf[g][y], bPb = cPb[g][y], bGf = cGf[g][y], bGb = cGb[g][y];
        if (e == 0.0f) { bPf = 0.0f; bPb = 0.0f; bGf = 0.0f; bGb = 0.0f; }
        // outward early-exit scan: a plane settles once r^2 >= its current best
        // (c[j] >= 0); wave stops when r^2 >= MAX over all live planes. Exact.
        float fr = 0.0f;
        for (int r = 1; r < NSIDE; ++r) {
            fr += 1.0f;
            float drr = fr * fr;
            float bmax = fmaxf(fmaxf(bPf, bPb), fmaxf(bGf, bGb));
            if (__all(drr >= bmax)) break;
            int jm = y - r, jp = y + r;
            int jmc = jm < 0 ? 0 : jm;
            int jpc = jp > (NSIDE - 1) ? (NSIDE - 1) : jp;
            float aPf = cPf[g][jmc], aPb = cPb[g][jmc], aGf = cGf[g][jmc], aGb = cGb[g][jmc];
            float ePf = cPf[g][jpc], ePb = cPb[g][jpc], eGf = cGf[g][jpc], eGb = cGb[g][jpc];
            if (jm < 0)         { aPf = 3e9f; aPb = 3e9f; aGf = 3e9f; aGb = 3e9f; }
            if (jp > NSIDE - 1) { ePf = 3e9f; ePb = 3e9f; eGf = 3e9f; eGb = 3e9f; }
            bPf = fminf(bPf, fminf(aPf, ePf) + drr);
            bPb = fminf(bPb, fminf(aPb, ePb) + drr);
            bGf = fminf(bGf, fminf(aGf, eGf) + drr);
            bGb = fminf(bGb, fminf(aGb, eGb) + drr);
        }
        float sP = e * (bPf + bPb);   // pred_dt^2 (one sense's sqEDT is 0 per pixel)
        float sG = e * (bGf + bGb);   // gt_dt^2
#pragma unroll
        for (int off = 32; off > 0; off >>= 1) {
            sP += __shfl_down(sP, off, 64);
            sG += __shfl_down(sG, off, 64);
        }
        if (lane == 0) { rP[wv] = sP; rG[wv] = sG; }
        __syncthreads();
        if (threadIdx.x == 0) {
#pragma unroll
            for (int i = 0; i < 16; ++i) { accP += rP[i]; accG += rG[i]; }
        }
        __syncthreads();   // rP/rG free for next round; c arrays free (readers done)
    }

    if (threadIdx.x == 0) {
        int hP = 0, hG = 0;
#pragma unroll
        for (int i = 0; i < 16; ++i) { hP |= oP[i]; hG |= oG[i]; }
        slot[blockIdx.x] = (hP ? accP : 0.0f) + (hG ? accG : 0.0f);
        __threadfence();                       // release slot before signaling
        int old = atomicAdd(cnt, 1);           // device-scope; 128 total
        lastFlag = (old == NBLK2 - 1) ? 1 : 0;
    }
    __syncthreads();
    if (lastFlag) {                            // block-uniform (LDS)
        __threadfence();                       // acquire: see all slots
        if (threadIdx.x < NBLK2) {             // waves 0,1 reduce 128 slots
            float s = slot[threadIdx.x];
#pragma unroll
            for (int off = 32; off > 0; off >>= 1) s += __shfl_down(s, off, 64);
            if (lane == 0) fin[wv] = s;
        }
        __syncthreads();
        if (threadIdx.x == 0)
            out[0] = (fin[0] + fin[1]) * (1.0f / (float)(NB * HW));
    }
}

extern "C" void kernel_launch(void* const* d_in, const int* in_sizes, int n_in,
                              void* d_out, int out_size, void* d_ws, size_t ws_size,
                              hipStream_t stream) {
    const float* mo = (const float*)d_in[0];
    const float* gt = (const float*)d_in[1];
    float* out = (float*)d_out;
    char* ws = (char*)d_ws;

    u64* zzw    = (u64*)(ws + ZZ_OFF);
    int* cnt    = (int*)(ws + CNT_OFF);
    float* slot = (float*)(ws + SLOT_OFF);

    hipLaunchKernelGGL(k_bits,     dim3(NMAP * 256), dim3(256),  0, stream, mo, gt, zzw, cnt);
    hipLaunchKernelGGL(k_colfinal, dim3(NBLK2),      dim3(1024), 0, stream, zzw, slot, cnt, out);
}